// Round 2
// baseline (3014.062 us; speedup 1.0000x reference)
//
#include <hip/hip_runtime.h>

static constexpr int NN = 50000;   // nodes
static constexpr int NE = 800000;  // edges
// D = 128 features, hard-coded throughout.

__device__ __forceinline__ float clip100(float v) { return fminf(fmaxf(v, -100.f), 100.f); }

// ---------------- degree / normalization ----------------
__global__ __launch_bounds__(256) void k_deg_init(float* __restrict__ deg) {
    int i = blockIdx.x * 256 + threadIdx.x;
    if (i < NN) deg[i] = 1.f;  // self-loop
}

__global__ __launch_bounds__(256) void k_deg_count(const int* __restrict__ idx,
                                                   float* __restrict__ deg) {
    int e = blockIdx.x * 256 + threadIdx.x;
    if (e < NE) unsafeAtomicAdd(&deg[idx[NE + e]], 1.f);  // dst row of edge_index
}

__global__ __launch_bounds__(256) void k_deg_rsqrt(float* __restrict__ deg) {
    int i = blockIdx.x * 256 + threadIdx.x;
    if (i < NN) deg[i] = rsqrtf(fmaxf(deg[i], 1.f));
}

// ---------------- GEMM: C[n][j] = sum_k A[n][k] * W[k][j] ----------------
// A: f32 [NN][128] (optional clip to [-100,100]). W: f32 [128][128] row-major.
// W staged in LDS (64KB); 16-row A tiles in LDS (8KB); thread t handles rows
// {2*(t>>5), +1} x cols [4*(t&31) .. +3].
template <bool CLIP, bool ACC>
__global__ __launch_bounds__(256) void k_gemm128(const float* __restrict__ A,
                                                 const float* __restrict__ W,
                                                 float* __restrict__ C, int ntiles) {
    __shared__ float wf[128 * 128];
    __shared__ float af[16 * 128];
    const int tid = threadIdx.x;
    for (int i = tid; i < 128 * 128; i += 256) wf[i] = W[i];
    __syncthreads();

    const int jq = tid & 31;
    const int rh = tid >> 5;
    const int r0 = rh * 2, r1 = r0 + 1;
    float4* __restrict__ C4 = (float4*)C;

    for (int tile = blockIdx.x; tile < ntiles; tile += gridDim.x) {
        const long row0 = (long)tile * 16;
        for (int i = tid; i < 16 * 128; i += 256) {
            float v = A[row0 * 128 + i];
            if (CLIP) v = clip100(v);
            af[i] = v;
        }
        __syncthreads();

        const long o0 = (row0 + r0) * 32 + jq;
        const long o1 = (row0 + r1) * 32 + jq;
        float4 acc0, acc1;
        if (ACC) {
            acc0 = C4[o0];
            acc1 = C4[o1];
        } else {
            acc0 = make_float4(0.f, 0.f, 0.f, 0.f);
            acc1 = make_float4(0.f, 0.f, 0.f, 0.f);
        }

#pragma unroll 8
        for (int k = 0; k < 128; ++k) {
            const float4 w = *(const float4*)&wf[k * 128 + (jq << 2)];
            const float a0 = af[r0 * 128 + k];
            const float a1 = af[r1 * 128 + k];
            acc0.x = fmaf(a0, w.x, acc0.x);
            acc0.y = fmaf(a0, w.y, acc0.y);
            acc0.z = fmaf(a0, w.z, acc0.z);
            acc0.w = fmaf(a0, w.w, acc0.w);
            acc1.x = fmaf(a1, w.x, acc1.x);
            acc1.y = fmaf(a1, w.y, acc1.y);
            acc1.z = fmaf(a1, w.z, acc1.z);
            acc1.w = fmaf(a1, w.w, acc1.w);
        }
        C4[o0] = acc0;
        C4[o1] = acc1;
        __syncthreads();
    }
}

// ---------------- scatter (aggregation) ----------------
// B[i][:] = A[i][:] * dinv[i]^2   (self-loop contribution; also clears poison)
__global__ __launch_bounds__(256) void k_scat_init(const float* __restrict__ A,
                                                   float* __restrict__ B,
                                                   const float* __restrict__ dinv, int n4) {
    int i = blockIdx.x * 256 + threadIdx.x;
    if (i >= n4) return;
    const int row = i >> 5;
    const float d = dinv[row];
    const float s = d * d;
    float4 v = ((const float4*)A)[i];
    v.x *= s; v.y *= s; v.z *= s; v.w *= s;
    ((float4*)B)[i] = v;
}

// 32 lanes per edge; float4 gather of A[src], 4 fp32 atomics into B[dst]
__global__ __launch_bounds__(256) void k_scat_edges(const float* __restrict__ A,
                                                    float* __restrict__ B,
                                                    const int* __restrict__ idx,
                                                    const float* __restrict__ dinv) {
    const int t = blockIdx.x * 256 + threadIdx.x;
    const int e = t >> 5;
    if (e >= NE) return;
    const int q = t & 31;
    const int s = idx[e];
    const int d = idx[NE + e];
    const float nrm = dinv[s] * dinv[d];
    const float4 v = ((const float4*)A)[(long)s * 32 + q];
    float* p = B + (long)d * 128 + (q << 2);
    unsafeAtomicAdd(p + 0, v.x * nrm);
    unsafeAtomicAdd(p + 1, v.y * nrm);
    unsafeAtomicAdd(p + 2, v.z * nrm);
    unsafeAtomicAdd(p + 3, v.w * nrm);
}

// ---------------- epilogues ----------------
__global__ __launch_bounds__(256) void k_bias_relu(float* __restrict__ B,
                                                   const float* __restrict__ bias, int n4) {
    int i = blockIdx.x * 256 + threadIdx.x;
    if (i >= n4) return;
    const int j = (i & 31) << 2;
    float4 v = ((float4*)B)[i];
    v.x = fmaxf(v.x + bias[j + 0], 0.f);
    v.y = fmaxf(v.y + bias[j + 1], 0.f);
    v.z = fmaxf(v.z + bias[j + 2], 0.f);
    v.w = fmaxf(v.w + bias[j + 3], 0.f);
    ((float4*)B)[i] = v;
}

// B = relu(B + bias) + clip(x)
__global__ __launch_bounds__(256) void k_bias_relu_res(float* __restrict__ B,
                                                       const float* __restrict__ bias,
                                                       const float* __restrict__ x, int n4) {
    int i = blockIdx.x * 256 + threadIdx.x;
    if (i >= n4) return;
    const int j = (i & 31) << 2;
    float4 v = ((float4*)B)[i];
    const float4 xv = ((const float4*)x)[i];
    v.x = fmaxf(v.x + bias[j + 0], 0.f) + clip100(xv.x);
    v.y = fmaxf(v.y + bias[j + 1], 0.f) + clip100(xv.y);
    v.z = fmaxf(v.z + bias[j + 2], 0.f) + clip100(xv.z);
    v.w = fmaxf(v.w + bias[j + 3], 0.f) + clip100(xv.w);
    ((float4*)B)[i] = v;
}

// out = H * sigmoid(G + bg)
__global__ __launch_bounds__(256) void k_gate(const float* __restrict__ H,
                                              const float* __restrict__ G,
                                              const float* __restrict__ bg,
                                              float* __restrict__ out, int n4) {
    int i = blockIdx.x * 256 + threadIdx.x;
    if (i >= n4) return;
    const int j = (i & 31) << 2;
    const float4 h = ((const float4*)H)[i];
    float4 g = ((const float4*)G)[i];
    g.x = 1.f / (1.f + __expf(-(g.x + bg[j + 0])));
    g.y = 1.f / (1.f + __expf(-(g.y + bg[j + 1])));
    g.z = 1.f / (1.f + __expf(-(g.z + bg[j + 2])));
    g.w = 1.f / (1.f + __expf(-(g.w + bg[j + 3])));
    float4 o;
    o.x = h.x * g.x;
    o.y = h.y * g.y;
    o.z = h.z * g.z;
    o.w = h.w * g.w;
    ((float4*)out)[i] = o;
}

// ---------------- launch ----------------
extern "C" void kernel_launch(void* const* d_in, const int* in_sizes, int n_in,
                              void* d_out, int out_size, void* d_ws, size_t ws_size,
                              hipStream_t stream) {
    const float* x  = (const float*)d_in[0];
    const int*  eix = (const int*)d_in[1];
    const float* W1 = (const float*)d_in[2];
    const float* b1 = (const float*)d_in[3];
    const float* W2 = (const float*)d_in[4];
    const float* b2 = (const float*)d_in[5];
    const float* Wg = (const float*)d_in[6];
    const float* bg = (const float*)d_in[7];
    float* out = (float*)d_out;

    char* ws = (char*)d_ws;
    const size_t NB = (size_t)NN * 128 * sizeof(float);  // 25.6 MB
    float* bufA = (float*)ws;               // GEMM outputs / gate accumulator
    float* bufB = (float*)(ws + NB);        // aggregation accumulator / h
    float* dinv = (float*)(ws + 2 * NB);    // degree -> dinv

    const int n4 = NN * 32;                 // float4 count per feature map
    const int ntiles = NN / 16;             // 3125 (exact)
    dim3 blk(256);

    // normalization coefficients
    k_deg_init<<<(NN + 255) / 256, blk, 0, stream>>>(dinv);
    k_deg_count<<<(NE + 255) / 256, blk, 0, stream>>>(eix, dinv);
    k_deg_rsqrt<<<(NN + 255) / 256, blk, 0, stream>>>(dinv);

    // layer 1: t = clip(x) @ W1 ; agg ; h1 = relu(agg + b1)
    k_gemm128<true, false><<<1024, blk, 0, stream>>>(x, W1, bufA, ntiles);
    k_scat_init<<<(n4 + 255) / 256, blk, 0, stream>>>(bufA, bufB, dinv, n4);
    k_scat_edges<<<NE / 8, blk, 0, stream>>>(bufA, bufB, eix, dinv);
    k_bias_relu<<<(n4 + 255) / 256, blk, 0, stream>>>(bufB, b1, n4);

    // layer 2: t = h1 @ W2 ; agg ; h = relu(agg + b2) + clip(x)
    k_gemm128<false, false><<<1024, blk, 0, stream>>>(bufB, W2, bufA, ntiles);
    k_scat_init<<<(n4 + 255) / 256, blk, 0, stream>>>(bufA, bufB, dinv, n4);
    k_scat_edges<<<NE / 8, blk, 0, stream>>>(bufA, bufB, eix, dinv);
    k_bias_relu_res<<<(n4 + 255) / 256, blk, 0, stream>>>(bufB, b2, x, n4);

    // gate: G = h @ Wg[0:128] + clip(x) @ Wg[128:256] ; out = h * sigmoid(G + bg)
    k_gemm128<false, false><<<1024, blk, 0, stream>>>(bufB, Wg, bufA, ntiles);
    k_gemm128<true, true><<<1024, blk, 0, stream>>>(x, Wg + 128 * 128, bufA, ntiles);
    k_gate<<<(n4 + 255) / 256, blk, 0, stream>>>(bufB, bufA, bg, out, n4);
}

// Round 3
// 582.213 us; speedup vs baseline: 5.1769x; 5.1769x over previous
//
#include <hip/hip_runtime.h>

static constexpr int NN = 50000;   // nodes
static constexpr int NE = 800000;  // edges
// D = 128 features, hard-coded throughout.

__device__ __forceinline__ float clip100(float v) { return fminf(fmaxf(v, -100.f), 100.f); }

// ---------------- CSR build ----------------
__global__ __launch_bounds__(256) void k_zero(int* __restrict__ cnt) {
    int i = blockIdx.x * 256 + threadIdx.x;
    if (i < NN) cnt[i] = 0;
}

__global__ __launch_bounds__(256) void k_hist(const int* __restrict__ idx,
                                              int* __restrict__ cnt) {
    int e = blockIdx.x * 256 + threadIdx.x;
    if (e < NE) atomicAdd(&cnt[idx[NE + e]], 1);
}

// Single-block exclusive scan of cnt[0..NN) -> rowptr; also:
//   dinv[i] = rsqrt(1 + indeg)   (self-loop included)
//   cnt[i]  = rowptr[i]          (reused as the fill cursor)
__global__ __launch_bounds__(1024) void k_scan(int* __restrict__ cnt,
                                               int* __restrict__ rowptr,
                                               float* __restrict__ dinv) {
    __shared__ int ls[1024];
    const int t = threadIdx.x;
    const int CH = (NN + 1023) / 1024;  // 49
    const int beg = t * CH;
    const int end = min(NN, beg + CH);

    int sum = 0;
    for (int i = beg; i < end; ++i) sum += cnt[i];
    ls[t] = sum;
    __syncthreads();
    // Hillis-Steele inclusive scan over 1024 partial sums
    for (int off = 1; off < 1024; off <<= 1) {
        int v = ls[t];
        int u = (t >= off) ? ls[t - off] : 0;
        __syncthreads();
        ls[t] = v + u;
        __syncthreads();
    }
    int run = (t == 0) ? 0 : ls[t - 1];  // exclusive base
    for (int i = beg; i < end; ++i) {
        const int c = cnt[i];
        rowptr[i] = run;
        cnt[i] = run;  // fill cursor starts at row begin
        dinv[i] = rsqrtf(1.f + (float)c);
        run += c;
    }
    if (t == 0) rowptr[NN] = NE;
}

__global__ __launch_bounds__(256) void k_fill(const int* __restrict__ idx,
                                              int* __restrict__ cur,
                                              int* __restrict__ esrc) {
    int e = blockIdx.x * 256 + threadIdx.x;
    if (e >= NE) return;
    const int s = idx[e];
    const int d = idx[NE + e];
    const int pos = atomicAdd(&cur[d], 1);
    esrc[pos] = s;
}

// ---------------- GEMM: C[n][j] = sum_k A[n][k] * W[k][j] ----------------
template <bool CLIP, bool ACC>
__global__ __launch_bounds__(256) void k_gemm128(const float* __restrict__ A,
                                                 const float* __restrict__ W,
                                                 float* __restrict__ C, int ntiles) {
    __shared__ float wf[128 * 128];
    __shared__ float af[16 * 128];
    const int tid = threadIdx.x;
    for (int i = tid; i < 128 * 128; i += 256) wf[i] = W[i];
    __syncthreads();

    const int jq = tid & 31;
    const int rh = tid >> 5;
    const int r0 = rh * 2, r1 = r0 + 1;
    float4* __restrict__ C4 = (float4*)C;

    for (int tile = blockIdx.x; tile < ntiles; tile += gridDim.x) {
        const long row0 = (long)tile * 16;
        for (int i = tid; i < 16 * 128; i += 256) {
            float v = A[row0 * 128 + i];
            if (CLIP) v = clip100(v);
            af[i] = v;
        }
        __syncthreads();

        const long o0 = (row0 + r0) * 32 + jq;
        const long o1 = (row0 + r1) * 32 + jq;
        float4 acc0, acc1;
        if (ACC) {
            acc0 = C4[o0];
            acc1 = C4[o1];
        } else {
            acc0 = make_float4(0.f, 0.f, 0.f, 0.f);
            acc1 = make_float4(0.f, 0.f, 0.f, 0.f);
        }

#pragma unroll 8
        for (int k = 0; k < 128; ++k) {
            const float4 w = *(const float4*)&wf[k * 128 + (jq << 2)];
            const float a0 = af[r0 * 128 + k];
            const float a1 = af[r1 * 128 + k];
            acc0.x = fmaf(a0, w.x, acc0.x);
            acc0.y = fmaf(a0, w.y, acc0.y);
            acc0.z = fmaf(a0, w.z, acc0.z);
            acc0.w = fmaf(a0, w.w, acc0.w);
            acc1.x = fmaf(a1, w.x, acc1.x);
            acc1.y = fmaf(a1, w.y, acc1.y);
            acc1.z = fmaf(a1, w.z, acc1.z);
            acc1.w = fmaf(a1, w.w, acc1.w);
        }
        C4[o0] = acc0;
        C4[o1] = acc1;
        __syncthreads();
    }
}

// ---------------- fused aggregation ----------------
// One wave (64 lanes) per node d; lane owns cols [2*lane, 2*lane+1].
// B[d] = relu( sum_{e: dst=d} A[src_e]*dinv[s]*dinv[d] + A[d]*dinv[d]^2 + bias )
//        (+ clip(x[d]) if RES)
template <bool RES>
__global__ __launch_bounds__(256) void k_aggr(const float* __restrict__ A,
                                              float* __restrict__ B,
                                              const int* __restrict__ rowptr,
                                              const int* __restrict__ esrc,
                                              const float* __restrict__ dinv,
                                              const float* __restrict__ bias,
                                              const float* __restrict__ x) {
    const int d = (blockIdx.x * 256 + threadIdx.x) >> 6;  // wave id == node
    if (d >= NN) return;
    const int lane = threadIdx.x & 63;
    const float2* __restrict__ A2 = (const float2*)A;

    const float dd = dinv[d];
    float2 acc = A2[(long)d * 64 + lane];
    const float sl = dd * dd;
    acc.x *= sl;
    acc.y *= sl;

    const int beg = rowptr[d];
    const int end = rowptr[d + 1];
#pragma unroll 2
    for (int i = beg; i < end; ++i) {
        const int s = esrc[i];
        const float w = dinv[s] * dd;
        const float2 v = A2[(long)s * 64 + lane];
        acc.x = fmaf(v.x, w, acc.x);
        acc.y = fmaf(v.y, w, acc.y);
    }

    const float2 bv = ((const float2*)bias)[lane];
    acc.x = fmaxf(acc.x + bv.x, 0.f);
    acc.y = fmaxf(acc.y + bv.y, 0.f);
    if (RES) {
        const float2 xv = ((const float2*)x)[(long)d * 64 + lane];
        acc.x += clip100(xv.x);
        acc.y += clip100(xv.y);
    }
    ((float2*)B)[(long)d * 64 + lane] = acc;
}

// out = H * sigmoid(G + bg)   (H may alias out; per-thread read-before-write)
__global__ __launch_bounds__(256) void k_gate(const float* __restrict__ H,
                                              const float* __restrict__ G,
                                              const float* __restrict__ bg,
                                              float* __restrict__ out, int n4) {
    int i = blockIdx.x * 256 + threadIdx.x;
    if (i >= n4) return;
    const int j = (i & 31) << 2;
    const float4 h = ((const float4*)H)[i];
    float4 g = ((const float4*)G)[i];
    g.x = 1.f / (1.f + __expf(-(g.x + bg[j + 0])));
    g.y = 1.f / (1.f + __expf(-(g.y + bg[j + 1])));
    g.z = 1.f / (1.f + __expf(-(g.z + bg[j + 2])));
    g.w = 1.f / (1.f + __expf(-(g.w + bg[j + 3])));
    float4 o;
    o.x = h.x * g.x;
    o.y = h.y * g.y;
    o.z = h.z * g.z;
    o.w = h.w * g.w;
    ((float4*)out)[i] = o;
}

// ---------------- launch ----------------
extern "C" void kernel_launch(void* const* d_in, const int* in_sizes, int n_in,
                              void* d_out, int out_size, void* d_ws, size_t ws_size,
                              hipStream_t stream) {
    const float* x  = (const float*)d_in[0];
    const int*  eix = (const int*)d_in[1];
    const float* W1 = (const float*)d_in[2];
    const float* b1 = (const float*)d_in[3];
    const float* W2 = (const float*)d_in[4];
    const float* b2 = (const float*)d_in[5];
    const float* Wg = (const float*)d_in[6];
    const float* bg = (const float*)d_in[7];
    float* out = (float*)d_out;

    char* ws = (char*)d_ws;
    const size_t NB = (size_t)NN * 128 * sizeof(float);  // 25.6 MB
    float* bufA   = (float*)ws;                         // GEMM outputs / gate acc
    int*   cnt    = (int*)(ws + NB);                    // histogram -> fill cursor
    int*   rowptr = (int*)(ws + NB + 1 * 200704);       // NN+1 ints (padded region)
    float* dinv   = (float*)(ws + NB + 2 * 200704);
    int*   esrc   = (int*)(ws + NB + 3 * 200704);       // NE ints
    float* bufB   = out;                                // H buffer aliases d_out

    const int n4 = NN * 32;
    const int ntiles = NN / 16;  // 3125
    dim3 blk(256);

    // CSR + normalization
    k_zero<<<(NN + 255) / 256, blk, 0, stream>>>(cnt);
    k_hist<<<(NE + 255) / 256, blk, 0, stream>>>(eix, cnt);
    k_scan<<<1, 1024, 0, stream>>>(cnt, rowptr, dinv);
    k_fill<<<(NE + 255) / 256, blk, 0, stream>>>(eix, cnt, esrc);

    // layer 1: t = clip(x) @ W1 ; h1 = relu(agg(t) + b1)   (h1 in bufB)
    k_gemm128<true, false><<<1024, blk, 0, stream>>>(x, W1, bufA, ntiles);
    k_aggr<false><<<(NN * 64 + 255) / 256, blk, 0, stream>>>(bufA, bufB, rowptr, esrc,
                                                             dinv, b1, nullptr);

    // layer 2: t = h1 @ W2 ; h = relu(agg(t) + b2) + clip(x)   (h in bufB)
    k_gemm128<false, false><<<1024, blk, 0, stream>>>(bufB, W2, bufA, ntiles);
    k_aggr<true><<<(NN * 64 + 255) / 256, blk, 0, stream>>>(bufA, bufB, rowptr, esrc,
                                                            dinv, b2, x);

    // gate: G = h @ Wg[0:128] + clip(x) @ Wg[128:256] ; out = h * sigmoid(G + bg)
    k_gemm128<false, false><<<1024, blk, 0, stream>>>(bufB, Wg, bufA, ntiles);
    k_gemm128<true, true><<<1024, blk, 0, stream>>>(x, Wg + 128 * 128, bufA, ntiles);
    k_gate<<<(n4 + 255) / 256, blk, 0, stream>>>(bufB, bufA, bg, out, n4);
}

// Round 4
// 469.444 us; speedup vs baseline: 6.4205x; 1.2402x over previous
//
#include <hip/hip_runtime.h>

static constexpr int NN = 50000;   // nodes
static constexpr int NE = 800000;  // edges
static constexpr int NBLK = (NN + 255) / 256;  // 196 scan blocks
// D = 128 features, hard-coded throughout.

__device__ __forceinline__ float clip100(float v) { return fminf(fmaxf(v, -100.f), 100.f); }

// ---------------- CSR build ----------------
__global__ __launch_bounds__(256) void k_zero(int* __restrict__ cnt) {
    int i = blockIdx.x * 256 + threadIdx.x;
    if (i < NN) cnt[i] = 0;
}

__global__ __launch_bounds__(256) void k_hist(const int* __restrict__ idx,
                                              int* __restrict__ cnt) {
    int e = blockIdx.x * 256 + threadIdx.x;
    if (e < NE) atomicAdd(&cnt[idx[NE + e]], 1);
}

// per-block sums of cnt (coalesced)
__global__ __launch_bounds__(256) void k_bsum(const int* __restrict__ cnt,
                                              int* __restrict__ bsum) {
    __shared__ int ls[256];
    const int t = threadIdx.x;
    const int i = blockIdx.x * 256 + t;
    ls[t] = (i < NN) ? cnt[i] : 0;
    __syncthreads();
    for (int off = 128; off > 0; off >>= 1) {
        if (t < off) ls[t] += ls[t + off];
        __syncthreads();
    }
    if (t == 0) bsum[blockIdx.x] = ls[0];
}

// single block: exclusive scan of the NBLK partials -> bbase; rowptr[NN]=NE
__global__ __launch_bounds__(256) void k_scanb(const int* __restrict__ bsum,
                                               int* __restrict__ bbase,
                                               int* __restrict__ rowptr) {
    __shared__ int ls[256];
    const int t = threadIdx.x;
    ls[t] = (t < NBLK) ? bsum[t] : 0;
    __syncthreads();
    for (int off = 1; off < 256; off <<= 1) {
        const int add = (t >= off) ? ls[t - off] : 0;
        __syncthreads();
        ls[t] += add;
        __syncthreads();
    }
    if (t < NBLK) bbase[t] = (t == 0) ? 0 : ls[t - 1];
    if (t == 0) rowptr[NN] = NE;
}

// in-block exclusive scan + block base; writes rowptr, fill cursor, dinv
__global__ __launch_bounds__(256) void k_scan2(int* __restrict__ cnt,
                                               const int* __restrict__ bbase,
                                               int* __restrict__ rowptr,
                                               float* __restrict__ dinv) {
    __shared__ int ls[256];
    const int t = threadIdx.x;
    const int i = blockIdx.x * 256 + t;
    const int c = (i < NN) ? cnt[i] : 0;
    ls[t] = c;
    __syncthreads();
    for (int off = 1; off < 256; off <<= 1) {
        const int add = (t >= off) ? ls[t - off] : 0;
        __syncthreads();
        ls[t] += add;
        __syncthreads();
    }
    if (i < NN) {
        const int excl = bbase[blockIdx.x] + ls[t] - c;
        rowptr[i] = excl;
        cnt[i] = excl;  // fill cursor starts at row begin
        dinv[i] = rsqrtf(1.f + (float)c);
    }
}

__global__ __launch_bounds__(256) void k_fill(const int* __restrict__ idx,
                                              int* __restrict__ cur,
                                              int* __restrict__ esrc) {
    int e = blockIdx.x * 256 + threadIdx.x;
    if (e >= NE) return;
    const int s = idx[e];
    const int d = idx[NE + e];
    const int pos = atomicAdd(&cur[d], 1);
    esrc[pos] = s;
}

// ---------------- GEMM: C[n][j] = sum_k A[n][k] * W[k][j] ----------------
template <bool CLIP, bool ACC>
__global__ __launch_bounds__(256) void k_gemm128(const float* __restrict__ A,
                                                 const float* __restrict__ W,
                                                 float* __restrict__ C, int ntiles) {
    __shared__ float wf[128 * 128];
    __shared__ float af[16 * 128];
    const int tid = threadIdx.x;
    for (int i = tid; i < 128 * 128; i += 256) wf[i] = W[i];
    __syncthreads();

    const int jq = tid & 31;
    const int rh = tid >> 5;
    const int r0 = rh * 2, r1 = r0 + 1;
    float4* __restrict__ C4 = (float4*)C;

    for (int tile = blockIdx.x; tile < ntiles; tile += gridDim.x) {
        const long row0 = (long)tile * 16;
        for (int i = tid; i < 16 * 128; i += 256) {
            float v = A[row0 * 128 + i];
            if (CLIP) v = clip100(v);
            af[i] = v;
        }
        __syncthreads();

        const long o0 = (row0 + r0) * 32 + jq;
        const long o1 = (row0 + r1) * 32 + jq;
        float4 acc0, acc1;
        if (ACC) {
            acc0 = C4[o0];
            acc1 = C4[o1];
        } else {
            acc0 = make_float4(0.f, 0.f, 0.f, 0.f);
            acc1 = make_float4(0.f, 0.f, 0.f, 0.f);
        }

#pragma unroll 8
        for (int k = 0; k < 128; ++k) {
            const float4 w = *(const float4*)&wf[k * 128 + (jq << 2)];
            const float a0 = af[r0 * 128 + k];
            const float a1 = af[r1 * 128 + k];
            acc0.x = fmaf(a0, w.x, acc0.x);
            acc0.y = fmaf(a0, w.y, acc0.y);
            acc0.z = fmaf(a0, w.z, acc0.z);
            acc0.w = fmaf(a0, w.w, acc0.w);
            acc1.x = fmaf(a1, w.x, acc1.x);
            acc1.y = fmaf(a1, w.y, acc1.y);
            acc1.z = fmaf(a1, w.z, acc1.z);
            acc1.w = fmaf(a1, w.w, acc1.w);
        }
        C4[o0] = acc0;
        C4[o1] = acc1;
        __syncthreads();
    }
}

// ---------------- fused aggregation ----------------
// One wave (64 lanes) per node d; lane owns cols [2*lane, 2*lane+1].
// B[d] = relu( sum_{e: dst=d} A[src_e]*dinv[s]*dinv[d] + A[d]*dinv[d]^2 + bias )
//        (+ clip(x[d]) if RES)
template <bool RES>
__global__ __launch_bounds__(256) void k_aggr(const float* __restrict__ A,
                                              float* __restrict__ B,
                                              const int* __restrict__ rowptr,
                                              const int* __restrict__ esrc,
                                              const float* __restrict__ dinv,
                                              const float* __restrict__ bias,
                                              const float* __restrict__ x) {
    const int d = (blockIdx.x * 256 + threadIdx.x) >> 6;  // wave id == node
    if (d >= NN) return;
    const int lane = threadIdx.x & 63;
    const float2* __restrict__ A2 = (const float2*)A;

    const float dd = dinv[d];
    float2 acc = A2[(long)d * 64 + lane];
    const float sl = dd * dd;
    acc.x *= sl;
    acc.y *= sl;

    const int beg = rowptr[d];
    const int end = rowptr[d + 1];
#pragma unroll 2
    for (int i = beg; i < end; ++i) {
        const int s = esrc[i];
        const float w = dinv[s] * dd;
        const float2 v = A2[(long)s * 64 + lane];
        acc.x = fmaf(v.x, w, acc.x);
        acc.y = fmaf(v.y, w, acc.y);
    }

    const float2 bv = ((const float2*)bias)[lane];
    acc.x = fmaxf(acc.x + bv.x, 0.f);
    acc.y = fmaxf(acc.y + bv.y, 0.f);
    if (RES) {
        const float2 xv = ((const float2*)x)[(long)d * 64 + lane];
        acc.x += clip100(xv.x);
        acc.y += clip100(xv.y);
    }
    ((float2*)B)[(long)d * 64 + lane] = acc;
}

// out = H * sigmoid(G + bg)   (H may alias out; per-thread read-before-write)
__global__ __launch_bounds__(256) void k_gate(const float* __restrict__ H,
                                              const float* __restrict__ G,
                                              const float* __restrict__ bg,
                                              float* __restrict__ out, int n4) {
    int i = blockIdx.x * 256 + threadIdx.x;
    if (i >= n4) return;
    const int j = (i & 31) << 2;
    const float4 h = ((const float4*)H)[i];
    float4 g = ((const float4*)G)[i];
    g.x = 1.f / (1.f + __expf(-(g.x + bg[j + 0])));
    g.y = 1.f / (1.f + __expf(-(g.y + bg[j + 1])));
    g.z = 1.f / (1.f + __expf(-(g.z + bg[j + 2])));
    g.w = 1.f / (1.f + __expf(-(g.w + bg[j + 3])));
    float4 o;
    o.x = h.x * g.x;
    o.y = h.y * g.y;
    o.z = h.z * g.z;
    o.w = h.w * g.w;
    ((float4*)out)[i] = o;
}

// ---------------- launch ----------------
extern "C" void kernel_launch(void* const* d_in, const int* in_sizes, int n_in,
                              void* d_out, int out_size, void* d_ws, size_t ws_size,
                              hipStream_t stream) {
    const float* x  = (const float*)d_in[0];
    const int*  eix = (const int*)d_in[1];
    const float* W1 = (const float*)d_in[2];
    const float* b1 = (const float*)d_in[3];
    const float* W2 = (const float*)d_in[4];
    const float* b2 = (const float*)d_in[5];
    const float* Wg = (const float*)d_in[6];
    const float* bg = (const float*)d_in[7];
    float* out = (float*)d_out;

    char* ws = (char*)d_ws;
    const size_t NB = (size_t)NN * 128 * sizeof(float);  // 25.6 MB
    float* bufA   = (float*)ws;                          // GEMM outputs / gate acc
    int*   cnt    = (int*)(ws + NB);                     // histogram -> fill cursor
    int*   rowptr = (int*)(ws + NB + 1 * 200704);        // NN+1 ints (padded region)
    float* dinv   = (float*)(ws + NB + 2 * 200704);
    int*   bsum   = (int*)(ws + NB + 3 * 200704);        // NBLK ints
    int*   bbase  = (int*)(ws + NB + 3 * 200704 + 4096); // NBLK ints
    int*   esrc   = (int*)(ws + NB + 4 * 200704);        // NE ints
    float* bufB   = out;                                 // H buffer aliases d_out

    const int n4 = NN * 32;
    const int ntiles = NN / 16;  // 3125
    dim3 blk(256);

    // CSR + normalization (decomposed parallel scan)
    k_zero<<<NBLK, blk, 0, stream>>>(cnt);
    k_hist<<<(NE + 255) / 256, blk, 0, stream>>>(eix, cnt);
    k_bsum<<<NBLK, blk, 0, stream>>>(cnt, bsum);
    k_scanb<<<1, blk, 0, stream>>>(bsum, bbase, rowptr);
    k_scan2<<<NBLK, blk, 0, stream>>>(cnt, bbase, rowptr, dinv);
    k_fill<<<(NE + 255) / 256, blk, 0, stream>>>(eix, cnt, esrc);

    // layer 1: t = clip(x) @ W1 ; h1 = relu(agg(t) + b1)   (h1 in bufB)
    k_gemm128<true, false><<<1024, blk, 0, stream>>>(x, W1, bufA, ntiles);
    k_aggr<false><<<(NN * 64 + 255) / 256, blk, 0, stream>>>(bufA, bufB, rowptr, esrc,
                                                             dinv, b1, nullptr);

    // layer 2: t = h1 @ W2 ; h = relu(agg(t) + b2) + clip(x)   (h in bufB)
    k_gemm128<false, false><<<1024, blk, 0, stream>>>(bufB, W2, bufA, ntiles);
    k_aggr<true><<<(NN * 64 + 255) / 256, blk, 0, stream>>>(bufA, bufB, rowptr, esrc,
                                                            dinv, b2, x);

    // gate: G = h @ Wg[0:128] + clip(x) @ Wg[128:256] ; out = h * sigmoid(G + bg)
    k_gemm128<false, false><<<1024, blk, 0, stream>>>(bufB, Wg, bufA, ntiles);
    k_gemm128<true, true><<<1024, blk, 0, stream>>>(x, Wg + 128 * 128, bufA, ntiles);
    k_gate<<<(n4 + 255) / 256, blk, 0, stream>>>(bufB, bufA, bg, out, n4);
}